// Round 1
// baseline (1263.108 us; speedup 1.0000x reference)
//
#include <hip/hip_runtime.h>
#include <hip/hip_bf16.h>
#include <stdint.h>

typedef unsigned short u16;
typedef __bf16 bf16_t;
typedef bf16_t bf16x8 __attribute__((ext_vector_type(8)));
typedef u16    u16x8  __attribute__((ext_vector_type(8)));
typedef float  f32x4  __attribute__((ext_vector_type(4)));

#define BSZ    256
#define NATOMS 128
#define INF    128
#define HH     256
#define H3     768
#define MAXV   6
#define OUTF   256

__device__ __forceinline__ u16 f2bf(float f) {
  union { float f; unsigned u; } v; v.f = f;
  unsigned u = v.u;
  unsigned r = (u + 0x7FFFu + ((u >> 16) & 1u)) >> 16;  // RNE
  return (u16)r;
}
__device__ __forceinline__ float bf2f(u16 h) {
  union { unsigned u; float f; } v; v.u = ((unsigned)h) << 16;
  return v.f;
}
__device__ __forceinline__ f32x4 mfma_bf16(u16x8 a, u16x8 b, f32x4 c) {
  return __builtin_amdgcn_mfma_f32_16x16x32_bf16(
      __builtin_bit_cast(bf16x8, a), __builtin_bit_cast(bf16x8, b), c, 0, 0, 0);
}

// ---------------- prep: W_hh fp32 -> bf16 ----------------
__global__ void k_prep(const float* __restrict__ w, u16* __restrict__ o, int n) {
  int i = blockIdx.x * 256 + threadIdx.x;
  if (i < n) o[i] = f2bf(w[i]);
}

// ---------------- stage 1: x_proj = x @ W_ih^T + b_ih (bf16 out) ----------------
// M=32768, N=768, K=128. BM=BN=64, BK=32, 256 thr (4 waves, 2x2 of 32x32).
__global__ __launch_bounds__(256) void k_xproj(const float* __restrict__ X,
                                               const float* __restrict__ W,
                                               const float* __restrict__ bias,
                                               u16* __restrict__ out) {
  __shared__ __align__(16) u16 As[64][40];  // +8 pad: 2-way-only LDS conflicts
  __shared__ __align__(16) u16 Bs[64][40];
  const int m0 = blockIdx.x * 64, n0 = blockIdx.y * 64;
  const int tid = threadIdx.x, lane = tid & 63, wid = tid >> 6;
  const int wm = (wid & 1) * 32, wn = (wid >> 1) * 32;
  const int lrow = tid >> 2, lcol = (tid & 3) * 8;
  const f32x4 zero = {0.f, 0.f, 0.f, 0.f};
  f32x4 acc[2][2];
#pragma unroll
  for (int mi = 0; mi < 2; mi++)
#pragma unroll
    for (int ni = 0; ni < 2; ni++) acc[mi][ni] = zero;

  for (int kk = 0; kk < INF; kk += 32) {
    const float* ap = X + (size_t)(m0 + lrow) * INF + kk + lcol;
    const float* bp = W + (size_t)(n0 + lrow) * INF + kk + lcol;
    u16x8 av, bv;
#pragma unroll
    for (int j = 0; j < 8; j++) { av[j] = f2bf(ap[j]); bv[j] = f2bf(bp[j]); }
    *(u16x8*)&As[lrow][lcol] = av;
    *(u16x8*)&Bs[lrow][lcol] = bv;
    __syncthreads();
    u16x8 afr[2], bfr[2];
#pragma unroll
    for (int mi = 0; mi < 2; mi++)
      afr[mi] = *(const u16x8*)&As[wm + mi * 16 + (lane & 15)][(lane >> 4) * 8];
#pragma unroll
    for (int ni = 0; ni < 2; ni++)
      bfr[ni] = *(const u16x8*)&Bs[wn + ni * 16 + (lane & 15)][(lane >> 4) * 8];
#pragma unroll
    for (int mi = 0; mi < 2; mi++)
#pragma unroll
      for (int ni = 0; ni < 2; ni++) acc[mi][ni] = mfma_bf16(afr[mi], bfr[ni], acc[mi][ni]);
    __syncthreads();
  }
#pragma unroll
  for (int mi = 0; mi < 2; mi++)
#pragma unroll
    for (int ni = 0; ni < 2; ni++) {
      int n = n0 + wn + ni * 16 + (lane & 15);
      float bv = bias[n];
#pragma unroll
      for (int r = 0; r < 4; r++) {
        int m = m0 + wm + mi * 16 + (lane >> 4) * 4 + r;
        out[(size_t)m * H3 + n] = f2bf(acc[mi][ni][r] + bv);
      }
    }
}

// ---------------- stage 2: GRU recurrence, W_hh register-resident ----------------
// 16 blocks x 256 thr; block owns 16 batch rows for all 128 steps.
// Each wave holds a 192x256 W_hh slice as 96 B-fragments (384 VGPRs).
__global__ __launch_bounds__(256, 1) void k_gru(const u16* __restrict__ Whh,
                                                const float* __restrict__ bhh,
                                                const u16* __restrict__ xp,
                                                u16* __restrict__ rnn) {
  __shared__ __align__(16) u16 hA[16 * 264];   // bf16 h, A-operand layout (+8 pad)
  __shared__ float hF[16 * 256];               // fp32 h state
  __shared__ float gh[16 * 776];               // h @ Whh^T (+8 pad)
  __shared__ float bhh_s[H3];
  const int tid = threadIdx.x, lane = tid & 63, wid = tid >> 6;
  const int b0 = blockIdx.x * 16;

  for (int i = tid; i < 16 * 264; i += 256) hA[i] = 0;
  for (int i = tid; i < 16 * 256; i += 256) hF[i] = 0.f;
  for (int i = tid; i < H3; i += 256) bhh_s[i] = bhh[i];

  const int nbase = wid * 192;  // this wave's 192 gate rows
  u16x8 wf[12][8];
#pragma unroll
  for (int nt = 0; nt < 12; nt++)
#pragma unroll
    for (int kt = 0; kt < 8; kt++) {
      int n = nbase + nt * 16 + (lane & 15);
      int k = kt * 32 + (lane >> 4) * 8;
      wf[nt][kt] = *(const u16x8*)(Whh + (size_t)n * HH + k);
    }
  __syncthreads();

  for (int t = 0; t < NATOMS; t++) {
    // ---- gh = h @ Whh^T (MFMA, M=16 all valid) ----
    u16x8 af[8];
#pragma unroll
    for (int kt = 0; kt < 8; kt++)
      af[kt] = *(const u16x8*)&hA[(lane & 15) * 264 + kt * 32 + (lane >> 4) * 8];
    const f32x4 zero = {0.f, 0.f, 0.f, 0.f};
#pragma unroll
    for (int np = 0; np < 6; np++) {
      f32x4 a0 = zero, a1 = zero;
#pragma unroll
      for (int kt = 0; kt < 8; kt++) {
        a0 = mfma_bf16(af[kt], wf[np * 2][kt], a0);
        a1 = mfma_bf16(af[kt], wf[np * 2 + 1][kt], a1);
      }
      int ncol = nbase + np * 32 + (lane & 15);
      int mrow = (lane >> 4) * 4;
#pragma unroll
      for (int r = 0; r < 4; r++) {
        gh[(mrow + r) * 776 + ncol] = a0[r];
        gh[(mrow + r) * 776 + ncol + 16] = a1[r];
      }
    }
    __syncthreads();
    // ---- gates + state update (fp32) ----
#pragma unroll 4
    for (int rep = 0; rep < 16; rep++) {
      int linear = rep * 256 + tid;
      int m = linear >> 8, i = linear & 255;
      size_t xbase = ((size_t)(b0 + m) * NATOMS + t) * H3;
      float xr = bf2f(xp[xbase + i]);
      float xz = bf2f(xp[xbase + 256 + i]);
      float xn = bf2f(xp[xbase + 512 + i]);
      float hr = gh[m * 776 + i] + bhh_s[i];
      float hz = gh[m * 776 + 256 + i] + bhh_s[256 + i];
      float hn = gh[m * 776 + 512 + i] + bhh_s[512 + i];
      float r = 1.f / (1.f + __expf(-(xr + hr)));
      float z = 1.f / (1.f + __expf(-(xz + hz)));
      float e = __expf(2.f * (xn + r * hn));   // tanh(x) = 1 - 2/(e^{2x}+1)
      float nn = 1.f - 2.f / (e + 1.f);
      float h = hF[m * 256 + i];
      float hnew = (1.f - z) * nn + z * h;
      hF[m * 256 + i] = hnew;
      u16 hb = f2bf(hnew);
      hA[m * 264 + i] = hb;
      rnn[((size_t)(b0 + m) * NATOMS + t) * HH + i] = hb;
    }
    __syncthreads();
  }
}

// ---------------- stage 3: out = leaky(gather(rnn) @ W_fc^T + b_fc) ----------------
// M=32768, N=256, K=1536; gather fused into A-tile load.
__global__ __launch_bounds__(256) void k_fc(const u16* __restrict__ rnn,
                                            const int* __restrict__ bonded,
                                            const float* __restrict__ W,
                                            const float* __restrict__ bias,
                                            float* __restrict__ out) {
  __shared__ __align__(16) u16 As[64][40];
  __shared__ __align__(16) u16 Bs[64][40];
  const int m0 = blockIdx.x * 64, n0 = blockIdx.y * 64;
  const int tid = threadIdx.x, lane = tid & 63, wid = tid >> 6;
  const int wm = (wid & 1) * 32, wn = (wid >> 1) * 32;
  const int lrow = tid >> 2, lcol = (tid & 3) * 8;
  const int m = m0 + lrow;
  const int b = m >> 7, atom = m & 127;
  const int* bptr = bonded + (size_t)(b * NATOMS + atom) * MAXV;
  const f32x4 zero = {0.f, 0.f, 0.f, 0.f};
  f32x4 acc[2][2];
#pragma unroll
  for (int mi = 0; mi < 2; mi++)
#pragma unroll
    for (int ni = 0; ni < 2; ni++) acc[mi][ni] = zero;

  for (int kk = 0; kk < HH * MAXV; kk += 32) {
    int k = kk + lcol;
    int v = k >> 8, kr = k & 255;
    int idx = bptr[v];
    u16x8 av = *(const u16x8*)(rnn + (size_t)(b * NATOMS + idx) * HH + kr);
    const float* wp = W + (size_t)(n0 + lrow) * (HH * MAXV) + k;
    u16x8 bv;
#pragma unroll
    for (int j = 0; j < 8; j++) bv[j] = f2bf(wp[j]);
    *(u16x8*)&As[lrow][lcol] = av;
    *(u16x8*)&Bs[lrow][lcol] = bv;
    __syncthreads();
    u16x8 afr[2], bfr[2];
#pragma unroll
    for (int mi = 0; mi < 2; mi++)
      afr[mi] = *(const u16x8*)&As[wm + mi * 16 + (lane & 15)][(lane >> 4) * 8];
#pragma unroll
    for (int ni = 0; ni < 2; ni++)
      bfr[ni] = *(const u16x8*)&Bs[wn + ni * 16 + (lane & 15)][(lane >> 4) * 8];
#pragma unroll
    for (int mi = 0; mi < 2; mi++)
#pragma unroll
      for (int ni = 0; ni < 2; ni++) acc[mi][ni] = mfma_bf16(afr[mi], bfr[ni], acc[mi][ni]);
    __syncthreads();
  }
#pragma unroll
  for (int mi = 0; mi < 2; mi++)
#pragma unroll
    for (int ni = 0; ni < 2; ni++) {
      int n = n0 + wn + ni * 16 + (lane & 15);
      float bv = bias[n];
#pragma unroll
      for (int r = 0; r < 4; r++) {
        int mm = m0 + wm + mi * 16 + (lane >> 4) * 4 + r;
        float vv = acc[mi][ni][r] + bv;
        out[(size_t)mm * OUTF + n] = vv >= 0.f ? vv : 0.1f * vv;
      }
    }
}

extern "C" void kernel_launch(void* const* d_in, const int* in_sizes, int n_in,
                              void* d_out, int out_size, void* d_ws, size_t ws_size,
                              hipStream_t stream) {
  const float* x      = (const float*)d_in[0];
  const int*   bonded = (const int*)d_in[1];
  const float* Wih    = (const float*)d_in[2];
  const float* Whh    = (const float*)d_in[3];
  const float* bih    = (const float*)d_in[4];
  const float* bhh    = (const float*)d_in[5];
  const float* Wfc    = (const float*)d_in[6];
  const float* bfc    = (const float*)d_in[7];
  float* out = (float*)d_out;

  char* ws = (char*)d_ws;
  u16* xp   = (u16*)(ws);                         // 32768*768*2  = 50,331,648 B
  u16* rnn  = (u16*)(ws + 50331648);              // 256*128*256*2 = 16,777,216 B
  u16* whhb = (u16*)(ws + 50331648 + 16777216);   // 768*256*2    =    393,216 B

  k_prep<<<768, 256, 0, stream>>>(Whh, whhb, H3 * HH);
  k_xproj<<<dim3(512, 12), 256, 0, stream>>>(x, Wih, bih, xp);
  k_gru<<<16, 256, 0, stream>>>(whhb, bhh, xp, rnn);
  k_fc<<<dim3(512, 4), 256, 0, stream>>>(rnn, bonded, Wfc, bfc, out);
}